// Round 2
// baseline (251.331 us; speedup 1.0000x reference)
//
#include <hip/hip_runtime.h>
#include <math.h>

// Problem constants
#define BATCH 8
#define NN 64
#define DD 65536            // 64*32*32 feature length (contiguous per [b,n])
#define BPB 64              // blocks per batch -> grid = 512
#define NBLK (BATCH * BPB)
#define KC (DD / BPB)       // 1024 K per block
#define KW (KC / 4)         // 256 K per wave (waves split K)
#define BKF 32              // K floats per staged tile (one MFMA K-step)
#define NT (KW / BKF)       // 8 tiles per wave
#define TILEF (NN * BKF)    // 2048 floats per tile (8 KB)
#define NTRI 10             // upper-triangle 16x16 tiles of the 64x64 Gram
#define PSZ (NTRI * 256)    // floats per tri partial (2560)

typedef float  floatx4 __attribute__((ext_vector_type(4)));
typedef __bf16 bf16x8  __attribute__((ext_vector_type(8)));

// Pack 8 fp32 -> 8 bf16 via v_perm_b32 (truncation; bias cancels in the
// scale-invariant cosine ratio — validated: absmax 1.5e-5).
static __device__ __forceinline__ bf16x8 cvt8(float4 lo, float4 hi) {
    const unsigned sel = 0x07060302u;
    union { unsigned u[4]; bf16x8 v; } r;
    r.u[0] = __builtin_amdgcn_perm(__float_as_uint(lo.y), __float_as_uint(lo.x), sel);
    r.u[1] = __builtin_amdgcn_perm(__float_as_uint(lo.w), __float_as_uint(lo.z), sel);
    r.u[2] = __builtin_amdgcn_perm(__float_as_uint(hi.y), __float_as_uint(hi.x), sel);
    r.u[3] = __builtin_amdgcn_perm(__float_as_uint(hi.w), __float_as_uint(hi.z), sel);
    return r.v;
}

// Init: zero the 8 per-batch arrival counters (workspace is poisoned).
__global__ __launch_bounds__(64) void init_kernel(unsigned* __restrict__ cnt) {
    if (threadIdx.x < BATCH) cnt[threadIdx.x] = 0u;
}

// ---------------------------------------------------------------------------
// Fused kernel, v2.
// Stage 1: wave-private double-buffered global_load_lds pipeline.
//   Each wave stages [64 rows][32 K] fp32 tiles (8 KB) into its own LDS
//   region with 8 x global_load_lds(width=16) per tile; counted
//   s_waitcnt vmcnt(8) keeps 16 loads (16 KB) in flight per wave at all
//   times -> ~128 KB/CU in flight -> HBM/L3 BW-bound (the register-staged
//   version measured 0.8 TB/s: compiler serialized loads, VGPR_Count=48).
//   LDS tile is XOR-swizzled (byte ^= (row&7)<<4) via pre-swizzled global
//   source addresses (gload_lds dest must be linear); ds_read_b128 at
//   row-stride 128B is then 2-way (free) instead of 16-way conflicted.
// Stage 2: cross-wave LDS reduce, wave 0 stores the block's tri partial
//   (plain stores — the R1 atomicAdd accumulate serialized 64-way).
// Stage 3: per-batch arrival counter; last block reduces the 64 partials
//   (float4 loads) and runs the CRF in LDS.
// ---------------------------------------------------------------------------
__global__ __launch_bounds__(256, 2) void fused_kernel(const float* __restrict__ a,
                                                       const float* __restrict__ logits,
                                                       const float* __restrict__ Wm,
                                                       float* __restrict__ part,
                                                       unsigned* __restrict__ cnt,
                                                       float* __restrict__ out) {
    // Union sized to exactly 64 KB (static LDS cap). lastFlag lives inside
    // the crf struct: it aliases red[], which is dead by the time tid0
    // writes it (wave-lockstep guarantees wave0's red reads precede).
    __shared__ __align__(16) union {
        float stage[4][2][TILEF];             // 64 KB: [wave][buf][tile]
        float red[3][NTRI][64][4];            // 30 KB: cross-wave reduce
        struct {
            int   lastFlag;
            float tri[PSZ];                   // reduced tri gram (10 KB)
            float G[NN][NN + 1];
            float E[NN];
            float nrm[NN];
            float part4[4 * NN];
        } crf;
    } sh;

    const int bid = blockIdx.x;
    const int b = bid >> 6;           // / BPB
    const int c = bid & (BPB - 1);

    const int tid  = threadIdx.x;
    const int w    = tid >> 6;        // wave id 0..3 -> K-subchunk
    const int lane = tid & 63;
    const int m    = lane & 15;
    const int q    = lane >> 4;

    // --- staging source (pre-swizzled so linear LDS dest == swizzled tile) -
    // LDS phys byte P = i*1024 + lane*16 -> row = i*8 + (lane>>3),
    // pcol = (lane&7)*16; logical col = pcol ^ ((row&7)<<4), row&7 = lane>>3.
    const int    srow = lane >> 3;
    const int    scol = ((((lane & 7) << 4) ^ (srow << 4)) >> 2);  // floats
    const float* gs = a + (size_t)b * NN * DD + (size_t)srow * DD
                        + (size_t)c * KC + (size_t)w * KW + scol;
    float* ldsW = &sh.stage[w][0][0];

    // --- LDS read offsets (swizzle constant per thread: row&7 == m&7) ------
    const int s1  = (m & 7) << 4;                    // byte swizzle
    const int loF = ((q << 5) ^ s1) >> 2;            // float offsets in row
    const int hiF = (((q << 5) + 16) ^ s1) >> 2;

    floatx4 acc[NTRI];
    #pragma unroll
    for (int i = 0; i < NTRI; ++i) acc[i] = (floatx4)0.0f;

#define STAGE(buf, t)                                                         \
    { _Pragma("unroll")                                                       \
      for (int i_ = 0; i_ < 8; ++i_)                                          \
          __builtin_amdgcn_global_load_lds(                                   \
              (const __attribute__((address_space(1))) void*)(gs + (size_t)i_ * 8 * DD + (t) * BKF), \
              (__attribute__((address_space(3))) void*)(ldsW + (buf) * TILEF + i_ * 256),            \
              16, 0, 0); }

    // acc slots: 0:(0,0) 1:(0,1) 2:(0,2) 3:(0,3) 4:(1,1) 5:(1,2) 6:(1,3)
    //            7:(2,2) 8:(2,3) 9:(3,3)
#define COMPUTE(buf)                                                          \
    {                                                                         \
        const float* tb = ldsW + (buf) * TILEF;                               \
        float4 l0 = *(const float4*)(tb + (m     ) * BKF + loF);              \
        float4 h0 = *(const float4*)(tb + (m     ) * BKF + hiF);              \
        float4 l1 = *(const float4*)(tb + (m + 16) * BKF + loF);              \
        float4 h1 = *(const float4*)(tb + (m + 16) * BKF + hiF);              \
        float4 l2 = *(const float4*)(tb + (m + 32) * BKF + loF);              \
        float4 h2 = *(const float4*)(tb + (m + 32) * BKF + hiF);              \
        float4 l3 = *(const float4*)(tb + (m + 48) * BKF + loF);              \
        float4 h3 = *(const float4*)(tb + (m + 48) * BKF + hiF);              \
        bf16x8 f0 = cvt8(l0, h0);                                             \
        bf16x8 f1 = cvt8(l1, h1);                                             \
        bf16x8 f2 = cvt8(l2, h2);                                             \
        bf16x8 f3 = cvt8(l3, h3);                                             \
        acc[0] = __builtin_amdgcn_mfma_f32_16x16x32_bf16(f0, f0, acc[0], 0, 0, 0); \
        acc[1] = __builtin_amdgcn_mfma_f32_16x16x32_bf16(f0, f1, acc[1], 0, 0, 0); \
        acc[2] = __builtin_amdgcn_mfma_f32_16x16x32_bf16(f0, f2, acc[2], 0, 0, 0); \
        acc[3] = __builtin_amdgcn_mfma_f32_16x16x32_bf16(f0, f3, acc[3], 0, 0, 0); \
        acc[4] = __builtin_amdgcn_mfma_f32_16x16x32_bf16(f1, f1, acc[4], 0, 0, 0); \
        acc[5] = __builtin_amdgcn_mfma_f32_16x16x32_bf16(f1, f2, acc[5], 0, 0, 0); \
        acc[6] = __builtin_amdgcn_mfma_f32_16x16x32_bf16(f1, f3, acc[6], 0, 0, 0); \
        acc[7] = __builtin_amdgcn_mfma_f32_16x16x32_bf16(f2, f2, acc[7], 0, 0, 0); \
        acc[8] = __builtin_amdgcn_mfma_f32_16x16x32_bf16(f2, f3, acc[8], 0, 0, 0); \
        acc[9] = __builtin_amdgcn_mfma_f32_16x16x32_bf16(f3, f3, acc[9], 0, 0, 0); \
    }

    // Prologue: 2 tiles in flight (16 loads/wave, 16 KB).
    STAGE(0, 0)
    STAGE(1, 1)
    #pragma unroll
    for (int t = 0; t < NT; ++t) {
        if (t < NT - 1) { asm volatile("s_waitcnt vmcnt(8)" ::: "memory"); }
        else            { asm volatile("s_waitcnt vmcnt(0)" ::: "memory"); }
        __builtin_amdgcn_sched_barrier(0);
        COMPUTE(t & 1)
        if (t + 2 < NT) {
            // ds_reads of this buffer must land before gload_lds overwrites it
            asm volatile("s_waitcnt lgkmcnt(0)" ::: "memory");
            __builtin_amdgcn_sched_barrier(0);
            STAGE(t & 1, t + 2)
        }
    }
#undef STAGE
#undef COMPUTE

    // --- cross-wave reduce (stage buffers are dead; barrier before alias) --
    __syncthreads();
    if (w > 0) {
        #pragma unroll
        for (int t = 0; t < NTRI; ++t)
            *(floatx4*)&sh.red[w - 1][t][lane][0] = acc[t];
    }
    __syncthreads();
    if (w == 0) {
        #pragma unroll
        for (int t = 0; t < NTRI; ++t) {
            floatx4 r0 = *(const floatx4*)&sh.red[0][t][lane][0];
            floatx4 r1 = *(const floatx4*)&sh.red[1][t][lane][0];
            floatx4 r2 = *(const floatx4*)&sh.red[2][t][lane][0];
            acc[t] += (r0 + r1) + r2;
        }
        // slot t holds G[16*ib + 4q + r][16*jb + m] (m89 layout, validated)
        float* pg = part + (size_t)bid * PSZ;
        #pragma unroll
        for (int t = 0; t < NTRI; ++t) {
            float* tp = pg + t * 256 + m;
            #pragma unroll
            for (int r = 0; r < 4; ++r)
                tp[(q * 4 + r) * 16] = acc[t][r];
        }
        __threadfence();   // release: partial visible before counter bump
    }
    if (tid == 0) {
        unsigned old = atomicAdd(cnt + b, 1u);
        sh.crf.lastFlag = (old == BPB - 1) ? 1 : 0;   // aliases dead red[]
    }
    __syncthreads();
    if (!sh.crf.lastFlag) return;

    // -----------------------------------------------------------------------
    // Last block of batch b: all 64 partials are in. Acquire, reduce them
    // (float4 columns), expand tri -> full 64x64, run the CRF.
    // -----------------------------------------------------------------------
    __threadfence();   // acquire side: invalidate caches, read fresh partials

    const float* pb = part + (size_t)b * BPB * PSZ;
    for (int fo = tid; fo < PSZ / 4; fo += 256) {      // 640 float4 columns
        float4 a0 = {0.f, 0.f, 0.f, 0.f}, a1 = a0, a2 = a0, a3 = a0;
        const float* p = pb + fo * 4;
        #pragma unroll 4
        for (int cc2 = 0; cc2 < BPB; cc2 += 4) {
            float4 v0 = *(const float4*)(p + (size_t)(cc2 + 0) * PSZ);
            float4 v1 = *(const float4*)(p + (size_t)(cc2 + 1) * PSZ);
            float4 v2 = *(const float4*)(p + (size_t)(cc2 + 2) * PSZ);
            float4 v3 = *(const float4*)(p + (size_t)(cc2 + 3) * PSZ);
            a0.x += v0.x; a0.y += v0.y; a0.z += v0.z; a0.w += v0.w;
            a1.x += v1.x; a1.y += v1.y; a1.z += v1.z; a1.w += v1.w;
            a2.x += v2.x; a2.y += v2.y; a2.z += v2.z; a2.w += v2.w;
            a3.x += v3.x; a3.y += v3.y; a3.z += v3.z; a3.w += v3.w;
        }
        float4 s;
        s.x = (a0.x + a1.x) + (a2.x + a3.x);
        s.y = (a0.y + a1.y) + (a2.y + a3.y);
        s.z = (a0.z + a1.z) + (a2.z + a3.z);
        s.w = (a0.w + a1.w) + (a2.w + a3.w);
        *(float4*)&sh.crf.tri[fo * 4] = s;
    }
    __syncthreads();

    // Expand tri layout to full G (K-partial Grams are symmetric).
    for (int idx = tid; idx < NN * NN; idx += 256) {
        int i  = idx >> 6, j = idx & 63;
        int ti = i >> 4, tj = j >> 4;
        int ib = ti <= tj ? ti : tj;
        int jb = ti <= tj ? tj : ti;
        int slot = ib * 4 - (ib * (ib - 1)) / 2 + (jb - ib);
        int rr = (ti <= tj) ? (i & 15) : (j & 15);
        int cc = (ti <= tj) ? (j & 15) : (i & 15);
        sh.crf.G[i][j] = sh.crf.tri[slot * 256 + rr * 16 + cc];
    }
    __syncthreads();

    const int ci = tid & 63;
    const int jq = tid >> 6;

    if (jq == 0) sh.crf.nrm[ci] = sqrtf(sh.crf.G[ci][ci]);
    sh.crf.E[ci] = 0.0f;
    __syncthreads();

    // pp in place: each (i,j) element owned by exactly one thread.
    const float ni = sh.crf.nrm[ci];
    #pragma unroll
    for (int jj = 0; jj < 16; ++jj) {
        int j = jq * 16 + jj;
        float wsym = 0.5f * (Wm[ci * NN + j] + Wm[j * NN + ci]);
        sh.crf.G[ci][j] = sh.crf.G[ci][j] / (ni * sh.crf.nrm[j] + 1e-6f) * wsym;
    }
    const float li = logits[b * NN + ci];
    __syncthreads();

    for (int it = 0; it < 10; ++it) {
        float acc2 = 0.0f;
        #pragma unroll
        for (int jj = 0; jj < 16; ++jj) {
            int j = jq * 16 + jj;
            float t = li + sh.crf.E[j];
            float s = 1.0f / (1.0f + expf(-t));
            acc2 = fmaf(2.0f * s - 1.0f, sh.crf.G[ci][j], acc2);
        }
        sh.crf.part4[jq * NN + ci] = acc2;
        __syncthreads();
        if (jq == 0)
            sh.crf.E[ci] = sh.crf.part4[ci] + sh.crf.part4[NN + ci]
                         + sh.crf.part4[2 * NN + ci] + sh.crf.part4[3 * NN + ci];
        __syncthreads();
    }

    if (tid < 64) {
        float s = sh.crf.E[tid];
        for (int off = 32; off > 0; off >>= 1) s += __shfl_down(s, off);
        float meanE = __shfl(s, 0) * (1.0f / 64.0f);
        out[b * NN + tid] = logits[b * NN + tid] + meanE;
    }
}

extern "C" void kernel_launch(void* const* d_in, const int* in_sizes, int n_in,
                              void* d_out, int out_size, void* d_ws, size_t ws_size,
                              hipStream_t stream) {
    const float* a      = (const float*)d_in[0];  // [8,64,64,32,32]
    const float* logits = (const float*)d_in[1];  // [8,64]
    const float* Wm     = (const float*)d_in[2];  // [1,64,64]
    float* out  = (float*)d_out;                  // [8,64]

    float*    part = (float*)d_ws;                        // [512][2560] fp32
    unsigned* cnt  = (unsigned*)(part + (size_t)NBLK * PSZ);   // [8]

    init_kernel<<<1, 64, 0, stream>>>(cnt);
    fused_kernel<<<NBLK, 256, 0, stream>>>(a, logits, Wm, part, cnt, out);
}

// Round 3
// 220.322 us; speedup vs baseline: 1.1407x; 1.1407x over previous
//
#include <hip/hip_runtime.h>
#include <math.h>

// Problem constants
#define BATCH 8
#define NN 64
#define DD 65536            // 64*32*32 feature length (contiguous per [b,n])
#define BPB 64              // blocks per batch -> grid = 512
#define NBLK (BATCH * BPB)
#define KC (DD / BPB)       // 1024 K per block
#define KW (KC / 4)         // 256 K per wave (waves split K)
#define KSTEPS (KW / 32)    // 8 MFMA K-steps per wave
#define NTRI 10             // upper-triangle 16x16 tiles of the 64x64 Gram
#define PSZ (NTRI * 256)    // floats per partial (2560)

typedef float  floatx4 __attribute__((ext_vector_type(4)));
typedef __bf16 bf16x8  __attribute__((ext_vector_type(8)));

// Pack 8 fp32 -> 8 bf16 via v_perm_b32 (truncation; bias cancels in the
// scale-invariant cosine ratio — validated: absmax 1.5e-5).
static __device__ __forceinline__ bf16x8 cvt8(float4 lo, float4 hi) {
    const unsigned sel = 0x07060302u;
    union { unsigned u[4]; bf16x8 v; } r;
    r.u[0] = __builtin_amdgcn_perm(__float_as_uint(lo.y), __float_as_uint(lo.x), sel);
    r.u[1] = __builtin_amdgcn_perm(__float_as_uint(lo.w), __float_as_uint(lo.z), sel);
    r.u[2] = __builtin_amdgcn_perm(__float_as_uint(hi.y), __float_as_uint(hi.x), sel);
    r.u[3] = __builtin_amdgcn_perm(__float_as_uint(hi.w), __float_as_uint(hi.z), sel);
    return r.v;
}

// ---------------------------------------------------------------------------
// Stage 1: per-chunk partial Gram, upper-triangle tiles only (R0 structure —
// measured best). ONE change vs R0: sched_barrier(0) after each LOADSET pins
// the 8-load groups so the compiler cannot sink loads to just-before-use
// (R1 evidence: VGPR_Count=48 proved the 16-float4 double-buffer was never
// live -> ~1 load in flight -> latency-serialized at <1 TB/s).
// __launch_bounds__ relaxed to (256,2) to give the now-live buffers VGPR
// headroom; grid is 2 blocks/CU regardless, so occupancy is unchanged.
// ---------------------------------------------------------------------------
__global__ __launch_bounds__(256, 2) void gram_partial_kernel(const float* __restrict__ a,
                                                              float* __restrict__ part) {
    __shared__ __align__(16) float red[3][NTRI][64][4];   // 30 KB

    const int bid = blockIdx.x;
    const int b = bid >> 6;           // / BPB
    const int c = bid & (BPB - 1);

    const int tid  = threadIdx.x;
    const int w    = tid >> 6;        // wave id 0..3 -> K-subchunk
    const int lane = tid & 63;
    const int m    = lane & 15;
    const int q    = lane >> 4;

    const float* base = a + (size_t)b * NN * DD + (size_t)c * KC + (size_t)w * KW
                          + (size_t)m * DD + q * 8;
    const float* p0 = base;                       // rows  0..15
    const float* p1 = base + (size_t)16 * DD;     // rows 16..31
    const float* p2 = base + (size_t)32 * DD;     // rows 32..47
    const float* p3 = base + (size_t)48 * DD;     // rows 48..63

    floatx4 acc[NTRI];
    #pragma unroll
    for (int i = 0; i < NTRI; ++i) acc[i] = (floatx4)0.0f;

    float4 A0, A1, A2, A3, A4, A5, A6, A7;   // buffer A
    float4 B0, B1, B2, B3, B4, B5, B6, B7;   // buffer B

#define LOADSET(R0,R1,R2,R3,R4,R5,R6,R7, o)                                \
    R0 = *(const float4*)(p0 + (o));  R1 = *(const float4*)(p0 + (o) + 4); \
    R2 = *(const float4*)(p1 + (o));  R3 = *(const float4*)(p1 + (o) + 4); \
    R4 = *(const float4*)(p2 + (o));  R5 = *(const float4*)(p2 + (o) + 4); \
    R6 = *(const float4*)(p3 + (o));  R7 = *(const float4*)(p3 + (o) + 4); \
    __builtin_amdgcn_sched_barrier(0);

    // acc slots: 0:(0,0) 1:(0,1) 2:(0,2) 3:(0,3) 4:(1,1) 5:(1,2) 6:(1,3)
    //            7:(2,2) 8:(2,3) 9:(3,3)
#define MFMASET(R0,R1,R2,R3,R4,R5,R6,R7)                                   \
    {                                                                      \
        bf16x8 f0 = cvt8(R0, R1);                                          \
        bf16x8 f1 = cvt8(R2, R3);                                          \
        bf16x8 f2 = cvt8(R4, R5);                                          \
        bf16x8 f3 = cvt8(R6, R7);                                          \
        acc[0] = __builtin_amdgcn_mfma_f32_16x16x32_bf16(f0, f0, acc[0], 0, 0, 0); \
        acc[1] = __builtin_amdgcn_mfma_f32_16x16x32_bf16(f0, f1, acc[1], 0, 0, 0); \
        acc[2] = __builtin_amdgcn_mfma_f32_16x16x32_bf16(f0, f2, acc[2], 0, 0, 0); \
        acc[3] = __builtin_amdgcn_mfma_f32_16x16x32_bf16(f0, f3, acc[3], 0, 0, 0); \
        acc[4] = __builtin_amdgcn_mfma_f32_16x16x32_bf16(f1, f1, acc[4], 0, 0, 0); \
        acc[5] = __builtin_amdgcn_mfma_f32_16x16x32_bf16(f1, f2, acc[5], 0, 0, 0); \
        acc[6] = __builtin_amdgcn_mfma_f32_16x16x32_bf16(f1, f3, acc[6], 0, 0, 0); \
        acc[7] = __builtin_amdgcn_mfma_f32_16x16x32_bf16(f2, f2, acc[7], 0, 0, 0); \
        acc[8] = __builtin_amdgcn_mfma_f32_16x16x32_bf16(f2, f3, acc[8], 0, 0, 0); \
        acc[9] = __builtin_amdgcn_mfma_f32_16x16x32_bf16(f3, f3, acc[9], 0, 0, 0); \
    }

    LOADSET(A0,A1,A2,A3,A4,A5,A6,A7, 0)
    #pragma unroll
    for (int s = 0; s < KSTEPS; s += 2) {
        LOADSET(B0,B1,B2,B3,B4,B5,B6,B7, (s + 1) * 32)
        MFMASET(A0,A1,A2,A3,A4,A5,A6,A7)
        if (s + 2 < KSTEPS) { LOADSET(A0,A1,A2,A3,A4,A5,A6,A7, (s + 2) * 32) }
        MFMASET(B0,B1,B2,B3,B4,B5,B6,B7)
    }
#undef LOADSET
#undef MFMASET

    // Cross-wave reduce: waves 1..3 dump accs to LDS; wave 0 sums + stores.
    if (w > 0) {
        #pragma unroll
        for (int t = 0; t < NTRI; ++t)
            *(floatx4*)&red[w - 1][t][lane][0] = acc[t];
    }
    __syncthreads();
    if (w == 0) {
        #pragma unroll
        for (int t = 0; t < NTRI; ++t) {
            floatx4 r0 = *(const floatx4*)&red[0][t][lane][0];
            floatx4 r1 = *(const floatx4*)&red[1][t][lane][0];
            floatx4 r2 = *(const floatx4*)&red[2][t][lane][0];
            acc[t] += (r0 + r1) + r2;
        }
        // slot t holds G[16*ib + 4q + r][16*jb + m] (m89 layout, validated)
        float* pg = part + (size_t)bid * PSZ;
        #pragma unroll
        for (int t = 0; t < NTRI; ++t) {
            float* tp = pg + t * 256 + m;
            #pragma unroll
            for (int r = 0; r < 4; ++r)
                tp[(q * 4 + r) * 16] = acc[t][r];
        }
    }
}

// ---------------------------------------------------------------------------
// Stage 1b: reduce BPB=64 tri-partials per batch -> gram[8][64*64] row-major.
// Lower triangle reconstructed by reading the transposed slot (each K-partial
// Gram is symmetric, so this is exact).
// ---------------------------------------------------------------------------
__global__ __launch_bounds__(128) void gram_reduce_kernel(const float* __restrict__ part,
                                                          float* __restrict__ gram) {
    const int gid = blockIdx.x * 128 + threadIdx.x;   // 0 .. 8*4096-1
    const int b   = gid >> 12;
    const int idx = gid & 4095;
    const int i   = idx >> 6;
    const int j   = idx & 63;
    const int ti  = i >> 4, tj = j >> 4;
    const int ib  = ti <= tj ? ti : tj;
    const int jb  = ti <= tj ? tj : ti;
    const int slot = ib * 4 - (ib * (ib - 1)) / 2 + (jb - ib);
    const int rr  = (ti <= tj) ? (i & 15) : (j & 15);
    const int cc  = (ti <= tj) ? (j & 15) : (i & 15);
    const int off = slot * 256 + rr * 16 + cc;
    const float* p = part + (size_t)b * BPB * PSZ + off;

    float s0 = 0.f, s1 = 0.f, s2 = 0.f, s3 = 0.f;
    #pragma unroll 4
    for (int c = 0; c < BPB; c += 4) {
        s0 += p[(size_t)(c + 0) * PSZ];
        s1 += p[(size_t)(c + 1) * PSZ];
        s2 += p[(size_t)(c + 2) * PSZ];
        s3 += p[(size_t)(c + 3) * PSZ];
    }
    gram[gid] = (s0 + s1) + (s2 + s3);
}

// ---------------------------------------------------------------------------
// Stage 2: per-batch CRF iterations. 8 blocks x 256 threads.
// ---------------------------------------------------------------------------
__global__ __launch_bounds__(256) void crf_kernel(const float* __restrict__ gram,
                                                  const float* __restrict__ logits,
                                                  const float* __restrict__ Wm,
                                                  float* __restrict__ out) {
    __shared__ float pp[NN][NN + 1];
    __shared__ float E[NN];
    __shared__ float nrm[NN];
    __shared__ float part[4 * NN];

    const int b  = blockIdx.x;
    const int tid = threadIdx.x;
    const int i  = tid & 63;
    const int jq = tid >> 6;
    const float* g = gram + b * NN * NN;

    if (jq == 0) nrm[i] = sqrtf(g[i * NN + i]);
    E[i] = 0.0f;
    __syncthreads();

    const float ni = nrm[i];
    for (int jj = 0; jj < 16; ++jj) {
        int j = jq * 16 + jj;
        float wsym = 0.5f * (Wm[i * NN + j] + Wm[j * NN + i]);
        pp[i][j] = g[i * NN + j] / (ni * nrm[j] + 1e-6f) * wsym;
    }
    const float li = logits[b * NN + i];
    __syncthreads();

    for (int it = 0; it < 10; ++it) {
        float acc = 0.0f;
        for (int jj = 0; jj < 16; ++jj) {
            int j = jq * 16 + jj;
            float t = li + E[j];
            float s = 1.0f / (1.0f + expf(-t));
            acc = fmaf(2.0f * s - 1.0f, pp[i][j], acc);
        }
        part[jq * NN + i] = acc;
        __syncthreads();
        if (jq == 0)
            E[i] = part[i] + part[NN + i] + part[2 * NN + i] + part[3 * NN + i];
        __syncthreads();
    }

    if (tid < 64) {
        float s = E[tid];
        for (int off = 32; off > 0; off >>= 1) s += __shfl_down(s, off);
        float meanE = __shfl(s, 0) * (1.0f / 64.0f);
        out[b * NN + tid] = logits[b * NN + tid] + meanE;
    }
}

extern "C" void kernel_launch(void* const* d_in, const int* in_sizes, int n_in,
                              void* d_out, int out_size, void* d_ws, size_t ws_size,
                              hipStream_t stream) {
    const float* a      = (const float*)d_in[0];  // [8,64,64,32,32]
    const float* logits = (const float*)d_in[1];  // [8,64]
    const float* Wm     = (const float*)d_in[2];  // [1,64,64]
    float* out  = (float*)d_out;                  // [8,64]

    float* part = (float*)d_ws;                           // [512][2560] fp32
    float* gram = part + (size_t)NBLK * PSZ;              // [8][4096]

    gram_partial_kernel<<<NBLK, 256, 0, stream>>>(a, part);
    gram_reduce_kernel<<<(BATCH * NN * NN) / 128, 128, 0, stream>>>(part, gram);
    crf_kernel<<<BATCH, 256, 0, stream>>>(gram, logits, Wm, out);
}